// Round 6
// baseline (125.606 us; speedup 1.0000x reference)
//
#include <hip/hip_runtime.h>
#include <hip/hip_bf16.h>

// B=4, S=4096, D=1024, H=64 single attention head.
// inputs fp32: x[4,4096,1024], Wq[1024,64], bq[64], Wk, bk, Wv, bv
// output fp32: [4,4096,64]

#define S_LEN 4096
#define D_MODEL 1024

typedef __attribute__((ext_vector_type(8))) short bf16x8;
typedef __attribute__((ext_vector_type(4))) float f32x4;
typedef __attribute__((ext_vector_type(16))) float f32x16;

__device__ inline short f2bf(float f) {
    union { float f; unsigned u; } v;
    v.f = f;
    unsigned r = v.u + 0x7fffu + ((v.u >> 16) & 1u);  // RNE
    return (short)(r >> 16);
}

__device__ inline unsigned cvt_pk(float lo, float hi) {
    unsigned r;
    asm("v_cvt_pk_bf16_f32 %0, %1, %2" : "=v"(r) : "v"(lo), "v"(hi));
    return r;
}

__device__ inline void pl32swap(unsigned& a, unsigned& b) {
    asm("v_permlane32_swap_b32 %0, %1" : "+v"(a), "+v"(b));
}

__device__ inline f32x16 fzero16() {
    f32x16 z;
#pragma unroll
    for (int i = 0; i < 16; ++i) z[i] = 0.f;
    return z;
}

// ---------------- kernel 1: W -> Wt bf16 [192][1024] via LDS transpose
// grid 48 = 3 mats x 16 k-tiles of 64; block 256.
__global__ void prep_w(const float* __restrict__ Wq, const float* __restrict__ Wk,
                       const float* __restrict__ Wv, short* __restrict__ Wt) {
    __shared__ short tile[64][72];                  // 16B-aligned rows
    int mat = blockIdx.x >> 4, kt = blockIdx.x & 15;
    const float* W = (mat == 0) ? Wq : (mat == 1 ? Wk : Wv);
    int tid = threadIdx.x;
    int h = tid & 63, kg = tid >> 6;
#pragma unroll
    for (int i = 0; i < 16; ++i) {
        int kl = kg * 16 + i;
        tile[h][kl] = f2bf(W[(size_t)(kt * 64 + kl) * 64 + h]);   // coalesced 256B rows
    }
    __syncthreads();
    int h2 = tid >> 2, c = tid & 3;                 // each thread: 16 shorts
    bf16x8 v0 = *(const bf16x8*)&tile[h2][c * 16];
    bf16x8 v1 = *(const bf16x8*)&tile[h2][c * 16 + 8];
    short* dst = Wt + (size_t)(mat * 64 + h2) * D_MODEL + kt * 64 + c * 16;
    *(bf16x8*)dst = v0;
    *(bf16x8*)(dst + 8) = v1;
}

// ---------------- kernel 2: QKV projection, 4-way split-K
// grid 1024 x 256 threads (4 waves): block = 16 rows, wave ks = K-chunk of 256.
__launch_bounds__(256, 4)
__global__ void proj_kernel(const float* __restrict__ x, const short* __restrict__ Wt,
                            const float* __restrict__ bq, const float* __restrict__ bk,
                            const float* __restrict__ bv,
                            short* __restrict__ Qb, short* __restrict__ Kb,
                            short* __restrict__ Vt) {
    __shared__ float psm[3 * 3264];                 // 39.2 KB; vsm aliases front
    int ks = threadIdx.x >> 6;
    int lane = threadIdx.x & 63;
    int g = lane >> 4, ln = lane & 15;
    int rowbase = blockIdx.x * 16;

    f32x4 acc[12];
#pragma unroll
    for (int i = 0; i < 12; ++i) acc[i] = (f32x4){0.f, 0.f, 0.f, 0.f};

    const float* xp = x + (size_t)(rowbase + ln) * D_MODEL + ks * 256 + g * 8;
    const short* wp = Wt + (size_t)ln * D_MODEL + ks * 256 + g * 8;

#pragma unroll 1
    for (int kk = 0; kk < 8; ++kk) {
        f32x4 a0 = *(const f32x4*)(xp + kk * 32);
        f32x4 a1 = *(const f32x4*)(xp + kk * 32 + 4);
        union { bf16x8 v; unsigned u[4]; } A;
        A.u[0] = cvt_pk(a0[0], a0[1]);
        A.u[1] = cvt_pk(a0[2], a0[3]);
        A.u[2] = cvt_pk(a1[0], a1[1]);
        A.u[3] = cvt_pk(a1[2], a1[3]);
#pragma unroll
        for (int nt = 0; nt < 12; ++nt) {
            bf16x8 bfr = *(const bf16x8*)(wp + (size_t)nt * 16 * D_MODEL + kk * 32);
            acc[nt] = __builtin_amdgcn_mfma_f32_16x16x32_bf16(A.v, bfr, acc[nt], 0, 0, 0);
        }
    }

    if (ks > 0) {
        float* st = psm + (ks - 1) * 3264;
#pragma unroll
        for (int nt = 0; nt < 12; ++nt)
#pragma unroll
            for (int r = 0; r < 4; ++r)
                st[nt * 272 + (g * 4 + r) * 17 + ln] = acc[nt][r];
    }
    __syncthreads();

    short vv[16];
    if (ks == 0) {
        const float* s0 = psm;
        const float* s1 = psm + 3264;
        const float* s2 = psm + 2 * 3264;
#pragma unroll
        for (int nt = 0; nt < 12; ++nt) {
            int proj = nt >> 2;
            int h = (nt & 3) * 16 + ln;
            float bias = (proj == 0 ? bq : (proj == 1 ? bk : bv))[h];
#pragma unroll
            for (int r = 0; r < 4; ++r) {
                int idx = nt * 272 + (g * 4 + r) * 17 + ln;
                float v = acc[nt][r] + s0[idx] + s1[idx] + s2[idx] + bias;
                short hv = f2bf(v);
                int srow = rowbase + g * 4 + r;
                if (proj == 0) {
                    Qb[(size_t)srow * 64 + h] = hv;
                } else if (proj == 1) {
                    Kb[(size_t)srow * 64 + h] = hv;
                } else {
                    vv[(nt & 3) * 4 + r] = hv;
                }
            }
        }
    }
    __syncthreads();                                 // psm reads done; alias as vsm
    short* vsm = (short*)psm;                        // [64][20] shorts
    if (ks == 0) {
#pragma unroll
        for (int nt = 0; nt < 4; ++nt) {
            int h = nt * 16 + ln;
#pragma unroll
            for (int r = 0; r < 4; ++r)
                vsm[h * 20 + g * 4 + r] = vv[nt * 4 + r];
        }
    }
    __syncthreads();
    {   // Vt writeout: thread = (h = t>>2, c = t&3 chunk of 4 s)
        int t = threadIdx.x;
        int h = t >> 2, c = t & 3;
        uint2 val = *(const uint2*)(vsm + h * 20 + c * 4);
        int bb = rowbase >> 12;
        int sg = (rowbase & 4095) + c * 4;
        *(uint2*)(Vt + (((size_t)(bb * 64 + h)) << 12) + sg) = val;
    }
}

// ---------------- kernel 3: flash attention, 32x32 MFMA, 8-way split-S
// grid 512 (4 batches x 128 q-tiles of 32) x 512 threads (8 waves).
// Wave w: keys [w*512, (w+1)*512) in 8 iters of 64. LDS only for final merge.
__launch_bounds__(512)
__global__ void attn_kernel(const short* __restrict__ Qb, const short* __restrict__ Kb,
                            const short* __restrict__ Vt, float* __restrict__ out) {
    __shared__ float osm[8 * 32 * 68];               // per-wave O^T staged as [q][68]
    __shared__ float mlsm[8 * 32 * 2];
    int lane = threadIdx.x & 63;
    int w = threadIdx.x >> 6;
    int l31 = lane & 31, hi = lane >> 5;
    int b = blockIdx.x >> 7, qt = blockIdx.x & 127;
    size_t qrow = ((size_t)b << 12) + (size_t)qt * 32;

    // Q B-frags: col q = l31, k-dim d = ks*16 + hi*8 + j
    bf16x8 qf[4];
    {
        const short* qp = Qb + (qrow + l31) * 64 + hi * 8;
#pragma unroll
        for (int ks = 0; ks < 4; ++ks) qf[ks] = *(const bf16x8*)(qp + ks * 16);
    }

    f32x16 oacc0 = fzero16(), oacc1 = fzero16();     // O^T[h][q], h-tiles 0,1
    float m = -1e30f, l = 0.f;                       // m in exp2 domain
    const float CEXP = 0.18033688011112042f;         // log2(e)/sqrt(64)

    const short* kp = Kb + (((size_t)b << 12) + w * 512 + l31) * 64 + hi * 8;
    const short* vp = Vt + ((size_t)b * 64 + l31) * S_LEN + w * 512 + hi * 8;

    for (int t = 0; t < 8; ++t) {
        // K A-frags: row = key (l31 within 32-tile), k-dim d
        bf16x8 kf[8];
        const short* kt0 = kp + (size_t)t * 64 * 64;
#pragma unroll
        for (int kt = 0; kt < 2; ++kt)
#pragma unroll
            for (int ks = 0; ks < 4; ++ks)
                kf[kt * 4 + ks] = *(const bf16x8*)(kt0 + (kt * 32) * 64 + ks * 16);

        f32x16 s0 = fzero16(), s1 = fzero16();       // S^T: row=k_local, col=q
#pragma unroll
        for (int ks = 0; ks < 4; ++ks) {
            s0 = __builtin_amdgcn_mfma_f32_32x32x16_bf16(kf[ks], qf[ks], s0, 0, 0, 0);
            s1 = __builtin_amdgcn_mfma_f32_32x32x16_bf16(kf[4 + ks], qf[ks], s1, 0, 0, 0);
        }

        // V A-frags (issue early): row = h (l31 + ht*32), k-dim = key window
        bf16x8 vf[8];
#pragma unroll
        for (int ht = 0; ht < 2; ++ht)
#pragma unroll
            for (int kk = 0; kk < 4; ++kk)
                vf[ht * 4 + kk] = *(const bf16x8*)(vp + (size_t)ht * 32 * S_LEN + t * 64 + kk * 16);

        // ---- tree max over this lane's 32 S-values
        float tm[16];
#pragma unroll
        for (int r = 0; r < 16; ++r) tm[r] = fmaxf(s0[r], s1[r]);
#pragma unroll
        for (int st = 8; st >= 1; st >>= 1)
#pragma unroll
            for (int r = 0; r < 8; ++r)
                if (r < st) tm[r] = fmaxf(tm[r], tm[r + st]);
        float pmax = tm[0] * CEXP;
        pmax = fmaxf(pmax, __shfl_xor(pmax, 32));
        if (!__all(pmax <= m + 8.f)) {               // defer-max (THR=8)
            float mn = fmaxf(m, pmax);
            float fsc = exp2f(m - mn);
            m = mn;
            l *= fsc;
#pragma unroll
            for (int r = 0; r < 16; ++r) { oacc0[r] *= fsc; oacc1[r] *= fsc; }
        }

        // ---- exponentials + tree row-sum
        float p0[16], p1[16];
#pragma unroll
        for (int r = 0; r < 16; ++r) p0[r] = exp2f(s0[r] * CEXP - m);
#pragma unroll
        for (int r = 0; r < 16; ++r) p1[r] = exp2f(s1[r] * CEXP - m);
        float sa[16];
#pragma unroll
        for (int r = 0; r < 16; ++r) sa[r] = p0[r] + p1[r];
#pragma unroll
        for (int st = 8; st >= 1; st >>= 1)
#pragma unroll
            for (int r = 0; r < 8; ++r)
                if (r < st) sa[r] += sa[r + st];
        float rs = sa[0];

        // ---- pack P to bf16 B-frags (in-register, permlane32 swap)
#pragma unroll
        for (int kt = 0; kt < 2; ++kt) {
            const float* p = kt ? p1 : p0;
            unsigned D[8];
#pragma unroll
            for (int dw = 0; dw < 8; ++dw) D[dw] = cvt_pk(p[2 * dw], p[2 * dw + 1]);
            pl32swap(D[0], D[2]);
            pl32swap(D[1], D[3]);
            pl32swap(D[4], D[6]);
            pl32swap(D[5], D[7]);
            union { unsigned u[4]; bf16x8 v; } t0, t1;
            t0.u[0] = D[0]; t0.u[1] = D[1]; t0.u[2] = D[2]; t0.u[3] = D[3];
            t1.u[0] = D[4]; t1.u[1] = D[5]; t1.u[2] = D[6]; t1.u[3] = D[7];
            oacc0 = __builtin_amdgcn_mfma_f32_32x32x16_bf16(vf[kt * 2 + 0], t0.v, oacc0, 0, 0, 0);
            oacc1 = __builtin_amdgcn_mfma_f32_32x32x16_bf16(vf[4 + kt * 2 + 0], t0.v, oacc1, 0, 0, 0);
            oacc0 = __builtin_amdgcn_mfma_f32_32x32x16_bf16(vf[kt * 2 + 1], t1.v, oacc0, 0, 0, 0);
            oacc1 = __builtin_amdgcn_mfma_f32_32x32x16_bf16(vf[4 + kt * 2 + 1], t1.v, oacc1, 0, 0, 0);
        }
        rs += __shfl_xor(rs, 32);
        l += rs;
    }

    // ---- stage partials: O^T -> [q][h] layout, plus (m, l)
    {
        float* ow = osm + w * 2176 + l31 * 68;
#pragma unroll
        for (int r = 0; r < 16; ++r) {
            int h = (r & 3) + 8 * (r >> 2) + 4 * hi;
            ow[h] = oacc0[r];
            ow[32 + h] = oacc1[r];
        }
        if (hi == 0) {
            mlsm[(w * 32 + l31) * 2] = m;
            mlsm[(w * 32 + l31) * 2 + 1] = l;
        }
    }
    __syncthreads();

    // ---- merge 8 partials: thread = (q = t>>4, hb = (t&15)*4)
    {
        int tq = threadIdx.x >> 4, hb = (threadIdx.x & 15) * 4;
        float mw[8], lw[8];
#pragma unroll
        for (int w2 = 0; w2 < 8; ++w2) {
            mw[w2] = mlsm[(w2 * 32 + tq) * 2];
            lw[w2] = mlsm[(w2 * 32 + tq) * 2 + 1];
        }
        float M = mw[0];
#pragma unroll
        for (int w2 = 1; w2 < 8; ++w2) M = fmaxf(M, mw[w2]);
        f32x4 oa = (f32x4){0.f, 0.f, 0.f, 0.f};
        float lsum = 0.f;
#pragma unroll
        for (int w2 = 0; w2 < 8; ++w2) {
            float a = exp2f(mw[w2] - M);
            lsum += a * lw[w2];
            f32x4 x0 = *(const f32x4*)(osm + w2 * 2176 + tq * 68 + hb);
#pragma unroll
            for (int j = 0; j < 4; ++j) oa[j] += a * x0[j];
        }
        float inv = 1.f / lsum;
        f32x4 r0;
#pragma unroll
        for (int j = 0; j < 4; ++j) r0[j] = oa[j] * inv;
        *(f32x4*)(out + (qrow + tq) * 64 + hb) = r0;
    }
}

extern "C" void kernel_launch(void* const* d_in, const int* in_sizes, int n_in,
                              void* d_out, int out_size, void* d_ws, size_t ws_size,
                              hipStream_t stream) {
    const float* x  = (const float*)d_in[0];
    const float* Wq = (const float*)d_in[1];
    const float* bq = (const float*)d_in[2];
    const float* Wk = (const float*)d_in[3];
    const float* bk = (const float*)d_in[4];
    const float* Wv = (const float*)d_in[5];
    const float* bv = (const float*)d_in[6];

    short* ws = (short*)d_ws;
    short* Wt = ws;                       // 192*1024
    short* Qb = Wt + 192 * 1024;          // 16384*64
    short* Kb = Qb + 16384 * 64;
    short* Vt = Kb + 16384 * 64;          // [4][64][4096] transposed

    prep_w<<<48, 256, 0, stream>>>(Wq, Wk, Wv, Wt);
    proj_kernel<<<1024, 256, 0, stream>>>(x, Wt, bq, bk, bv, Qb, Kb, Vt);
    attn_kernel<<<512, 512, 0, stream>>>(Qb, Kb, Vt, (float*)d_out);
}

// Round 7
// 77.811 us; speedup vs baseline: 1.6142x; 1.6142x over previous
//
#include <hip/hip_runtime.h>
#include <hip/hip_bf16.h>

// B=4, S=4096, D=1024, H=64 single attention head.
// inputs fp32: x[4,4096,1024], Wq[1024,64], bq[64], Wk, bk, Wv, bv
// output fp32: [4,4096,64]

#define S_LEN 4096
#define D_MODEL 1024

typedef __attribute__((ext_vector_type(8))) short bf16x8;
typedef __attribute__((ext_vector_type(4))) float f32x4;
typedef __attribute__((ext_vector_type(16))) float f32x16;

__device__ inline short f2bf(float f) {
    union { float f; unsigned u; } v;
    v.f = f;
    unsigned r = v.u + 0x7fffu + ((v.u >> 16) & 1u);  // RNE
    return (short)(r >> 16);
}

__device__ inline unsigned cvt_pk(float lo, float hi) {
    unsigned r;
    asm("v_cvt_pk_bf16_f32 %0, %1, %2" : "=v"(r) : "v"(lo), "v"(hi));
    return r;
}

__device__ inline void pl32swap(unsigned& a, unsigned& b) {
    asm("v_permlane32_swap_b32 %0, %1" : "+v"(a), "+v"(b));
}

__device__ inline f32x16 fzero16() {
    f32x16 z;
#pragma unroll
    for (int i = 0; i < 16; ++i) z[i] = 0.f;
    return z;
}

// async global->LDS, 16B per lane, dest = lds_base + lane*16 (wave-uniform base)
__device__ inline void gload_lds16(const void* g, void* l) {
    __builtin_amdgcn_global_load_lds((const __attribute__((address_space(1))) void*)g,
                                     (__attribute__((address_space(3))) void*)l, 16, 0, 0);
}

// ---------------- kernel 1: W -> Wt bf16 [192][1024] via LDS transpose
__global__ void prep_w(const float* __restrict__ Wq, const float* __restrict__ Wk,
                       const float* __restrict__ Wv, short* __restrict__ Wt) {
    __shared__ short tile[64][72];
    int mat = blockIdx.x >> 4, kt = blockIdx.x & 15;
    const float* W = (mat == 0) ? Wq : (mat == 1 ? Wk : Wv);
    int tid = threadIdx.x;
    int h = tid & 63, kg = tid >> 6;
#pragma unroll
    for (int i = 0; i < 16; ++i) {
        int kl = kg * 16 + i;
        tile[h][kl] = f2bf(W[(size_t)(kt * 64 + kl) * 64 + h]);
    }
    __syncthreads();
    int h2 = tid >> 2, c = tid & 3;
    bf16x8 v0 = *(const bf16x8*)&tile[h2][c * 16];
    bf16x8 v1 = *(const bf16x8*)&tile[h2][c * 16 + 8];
    short* dst = Wt + (size_t)(mat * 64 + h2) * D_MODEL + kt * 64 + c * 16;
    *(bf16x8*)dst = v0;
    *(bf16x8*)(dst + 8) = v1;
}

// ---------------- kernel 2: QKV projection, LDS-staged GEMM
// grid 256 x 512 threads (8 waves). Block = 64 rows x 192 cols, K=1024 in 16 BK=64 steps.
// Wave (rt = w>>1: 16-row slice, nh = w&1: 96-col half). Wt tile [192][64] staged
// to LDS (double-buffered, XOR-swizzled via pre-swizzled global source).
__launch_bounds__(512)
__global__ void proj_kernel(const float* __restrict__ x, const short* __restrict__ Wt,
                            const float* __restrict__ bq, const float* __restrict__ bk,
                            const float* __restrict__ bv,
                            short* __restrict__ Qb, short* __restrict__ Kb,
                            short* __restrict__ Vt) {
    __shared__ __align__(16) char bsm[2 * 24576];    // Wt tile dbuf, 48 KB
    __shared__ short vsm[64][72];                    // V transpose staging
    int w = threadIdx.x >> 6;
    int lane = threadIdx.x & 63;
    int g = lane >> 4, ln = lane & 15;
    int rt = w >> 1, nh = w & 1;
    int rowbase = blockIdx.x * 64;

    const char* WtB = (const char*)Wt;

    // stage(buf, bk): this wave's 3KB slice; per-lane pre-swizzled source
    auto stageW = [&](int buf, int bk) {
#pragma unroll
        for (int i = 0; i < 3; ++i) {
            int od = w * 3072 + i * 1024 + lane * 16;
            int row = od >> 7, colb = od & 127;
            const char* src = WtB + (size_t)row * 2048 + bk * 128 + (colb ^ ((row & 7) << 4));
            gload_lds16(src, bsm + buf * 24576 + w * 3072 + i * 1024);
        }
    };

    f32x4 acc[6];
#pragma unroll
    for (int i = 0; i < 6; ++i) acc[i] = (f32x4){0.f, 0.f, 0.f, 0.f};

    const float* xw = x + (size_t)(rowbase + rt * 16 + ln) * D_MODEL + g * 8;

    // prologue: stage bk=0, load x bk=0
    stageW(0, 0);
    f32x4 A0 = *(const f32x4*)(xw);
    f32x4 A1 = *(const f32x4*)(xw + 4);
    f32x4 A2 = *(const f32x4*)(xw + 32);
    f32x4 A3 = *(const f32x4*)(xw + 36);
    __syncthreads();

    int cur = 0;
#pragma unroll 1
    for (int bk = 0; bk < 16; ++bk) {
        // prefetch next x + stage next Wt tile
        f32x4 N0, N1, N2, N3;
        if (bk < 15) {
            const float* xn = xw + (bk + 1) * 64;
            N0 = *(const f32x4*)(xn);
            N1 = *(const f32x4*)(xn + 4);
            N2 = *(const f32x4*)(xn + 32);
            N3 = *(const f32x4*)(xn + 36);
            stageW(cur ^ 1, bk + 1);
        }
        const char* bs = bsm + cur * 24576;
        // kk = 0
        {
            union { bf16x8 v; unsigned u[4]; } A;
            A.u[0] = cvt_pk(A0[0], A0[1]);
            A.u[1] = cvt_pk(A0[2], A0[3]);
            A.u[2] = cvt_pk(A1[0], A1[1]);
            A.u[3] = cvt_pk(A1[2], A1[3]);
#pragma unroll
            for (int nt = 0; nt < 6; ++nt) {
                int row = nh * 96 + nt * 16 + ln;
                bf16x8 bfr = *(const bf16x8*)(bs + row * 128 + ((g * 16) ^ ((row & 7) << 4)));
                acc[nt] = __builtin_amdgcn_mfma_f32_16x16x32_bf16(A.v, bfr, acc[nt], 0, 0, 0);
            }
        }
        // kk = 1
        {
            union { bf16x8 v; unsigned u[4]; } A;
            A.u[0] = cvt_pk(A2[0], A2[1]);
            A.u[1] = cvt_pk(A2[2], A2[3]);
            A.u[2] = cvt_pk(A3[0], A3[1]);
            A.u[3] = cvt_pk(A3[2], A3[3]);
#pragma unroll
            for (int nt = 0; nt < 6; ++nt) {
                int row = nh * 96 + nt * 16 + ln;
                bf16x8 bfr = *(const bf16x8*)(bs + row * 128 + ((64 + g * 16) ^ ((row & 7) << 4)));
                acc[nt] = __builtin_amdgcn_mfma_f32_16x16x32_bf16(A.v, bfr, acc[nt], 0, 0, 0);
            }
        }
        __syncthreads();
        if (bk < 15) { A0 = N0; A1 = N1; A2 = N2; A3 = N3; }
        cur ^= 1;
    }

    // epilogue: bias + writes. Global col c = nh*96 + nt*16 + ln.
#pragma unroll
    for (int nt = 0; nt < 6; ++nt) {
        int c = nh * 96 + nt * 16 + ln;
        int proj = c >> 6;
        int h = c & 63;
        float bias = (proj == 0 ? bq : (proj == 1 ? bk : bv))[h];
#pragma unroll
        for (int r = 0; r < 4; ++r) {
            int srow = rowbase + rt * 16 + g * 4 + r;
            float v = acc[nt][r] + bias;
            short hv = f2bf(v);
            if (proj == 0) {
                Qb[(size_t)srow * 64 + h] = hv;
            } else if (proj == 1) {
                Kb[(size_t)srow * 64 + h] = hv;
            } else {
                vsm[h][rt * 16 + g * 4 + r] = hv;     // V: stage for coalesced transpose
            }
        }
    }
    __syncthreads();
    {   // coalesced Vt writeout: thread = (h = t>>3, c = t&7): 16B of 8 rows
        int t = threadIdx.x;
        int h = t >> 3, c = t & 7;
        bf16x8 val = *(const bf16x8*)&vsm[h][c * 8];
        int bb = rowbase >> 12;
        int sg = (rowbase & 4095) + c * 8;
        *(bf16x8*)(Vt + ((size_t)(bb * 64 + h) << 12) + sg) = val;
    }
}

// ---------------- kernel 3: flash attention, LDS-staged K/V, 4-way split-S in-block
// grid 256 (4 b x 64 q-supertiles of 64 rows) x 512 threads (8 waves).
// Wave (sp = w>>1: key range sp*1024.., qt = w&1: q-subtile of 32).
// Per sp-group: K double-buffered (staged by qt0 wave), V per-iter (staged by qt1 wave).
__launch_bounds__(512)
__global__ void attn_kernel(const short* __restrict__ Qb, const short* __restrict__ Kb,
                            const short* __restrict__ Vt, float* __restrict__ out) {
    __shared__ __align__(16) char smraw[98304];      // [4 sp][K0 8K | K1 8K | V 8K]; merge aliases front
    int lane = threadIdx.x & 63;
    int w = threadIdx.x >> 6;
    int l31 = lane & 31, hi = lane >> 5;
    int sp = w >> 1, qt = w & 1;
    int b = blockIdx.x >> 6, qs = blockIdx.x & 63;
    size_t qrow0 = ((size_t)b << 12) + (size_t)qs * 64;

    char* kbuf0 = smraw + sp * 24576;
    char* kbuf1 = kbuf0 + 8192;
    char* vbuf  = kbuf0 + 16384;

    const char* KB = (const char*)(Kb + (((size_t)b << 12) + sp * 1024) * 64);
    const char* VB = (const char*)Vt;

    // stage K tile t (8KB: [64 keys][128B d], swizzled) — qt==0 wave
    auto stageK = [&](char* dst, int t) {
#pragma unroll
        for (int i = 0; i < 8; ++i) {
            int od = i * 1024 + lane * 16;
            int row = od >> 7, colb = od & 127;
            const char* src = KB + (size_t)(t * 64 + row) * 128 + (colb ^ ((row & 7) << 4));
            gload_lds16(src, dst + i * 1024);
        }
    };
    // stage V^T tile t (8KB: [64 h][128B keys], swizzled) — qt==1 wave
    auto stageV = [&](char* dst, int t) {
#pragma unroll
        for (int i = 0; i < 8; ++i) {
            int od = i * 1024 + lane * 16;
            int row = od >> 7, colb = od & 127;
            const char* src = VB + ((size_t)(b * 64 + row) << 13) + (sp * 1024 + t * 64) * 2
                              + (colb ^ ((row & 7) << 4));
            gload_lds16(src, dst + i * 1024);
        }
    };

    // Q B-frags: col q = l31, k-dim d = ks*16 + hi*8 + j
    bf16x8 qf[4];
    {
        const short* qp = Qb + (qrow0 + qt * 32 + l31) * 64 + hi * 8;
#pragma unroll
        for (int ks = 0; ks < 4; ++ks) qf[ks] = *(const bf16x8*)(qp + ks * 16);
    }

    f32x16 oacc0 = fzero16(), oacc1 = fzero16();     // O^T[h][q]
    float m = -1e30f, l = 0.f;
    const float CEXP = 0.18033688011112042f;         // log2(e)/sqrt(64)
    int swz = (l31 & 7) << 4;

    if (qt == 0) stageK(kbuf0, 0);
    __syncthreads();

    for (int t = 0; t < 16; ++t) {
        char* kc = (t & 1) ? kbuf1 : kbuf0;
        char* kn = (t & 1) ? kbuf0 : kbuf1;
        if (qt == 0 && t < 15) stageK(kn, t + 1);
        if (qt == 1) stageV(vbuf, t);

        // ---- K frags from LDS + QK^T
        bf16x8 kf[8];
#pragma unroll
        for (int kt = 0; kt < 2; ++kt)
#pragma unroll
            for (int ks = 0; ks < 4; ++ks)
                kf[kt * 4 + ks] = *(const bf16x8*)(kc + (kt * 32 + l31) * 128
                                                  + ((ks * 32 + hi * 16) ^ swz));
        f32x16 s0 = fzero16(), s1 = fzero16();       // S^T: row=k_local, col=q=l31
#pragma unroll
        for (int ks = 0; ks < 4; ++ks) {
            s0 = __builtin_amdgcn_mfma_f32_32x32x16_bf16(kf[ks], qf[ks], s0, 0, 0, 0);
            s1 = __builtin_amdgcn_mfma_f32_32x32x16_bf16(kf[4 + ks], qf[ks], s1, 0, 0, 0);
        }

        // ---- online softmax (tree), defer-max
        float tm[16];
#pragma unroll
        for (int r = 0; r < 16; ++r) tm[r] = fmaxf(s0[r], s1[r]);
#pragma unroll
        for (int st = 8; st >= 1; st >>= 1)
#pragma unroll
            for (int r = 0; r < 8; ++r)
                if (r < st) tm[r] = fmaxf(tm[r], tm[r + st]);
        float pmax = tm[0] * CEXP;
        pmax = fmaxf(pmax, __shfl_xor(pmax, 32));
        if (!__all(pmax <= m + 8.f)) {
            float mn = fmaxf(m, pmax);
            float fsc = exp2f(m - mn);
            m = mn;
            l *= fsc;
#pragma unroll
            for (int r = 0; r < 16; ++r) { oacc0[r] *= fsc; oacc1[r] *= fsc; }
        }
        float p0[16], p1[16];
#pragma unroll
        for (int r = 0; r < 16; ++r) p0[r] = exp2f(s0[r] * CEXP - m);
#pragma unroll
        for (int r = 0; r < 16; ++r) p1[r] = exp2f(s1[r] * CEXP - m);
        float sa[16];
#pragma unroll
        for (int r = 0; r < 16; ++r) sa[r] = p0[r] + p1[r];
#pragma unroll
        for (int st = 8; st >= 1; st >>= 1)
#pragma unroll
            for (int r = 0; r < 8; ++r)
                if (r < st) sa[r] += sa[r + st];
        float rs = sa[0];
        rs += __shfl_xor(rs, 32);
        l += rs;

        // ---- pack P (verified r6 mapping): 2 key-32 tiles -> 4 B-frag tuples
        union { unsigned u[4]; bf16x8 v; } t00, t01, t10, t11;
        {
            unsigned D[8];
#pragma unroll
            for (int dw = 0; dw < 8; ++dw) D[dw] = cvt_pk(p0[2 * dw], p0[2 * dw + 1]);
            pl32swap(D[0], D[2]); pl32swap(D[1], D[3]);
            pl32swap(D[4], D[6]); pl32swap(D[5], D[7]);
            t00.u[0] = D[0]; t00.u[1] = D[1]; t00.u[2] = D[2]; t00.u[3] = D[3];
            t01.u[0] = D[4]; t01.u[1] = D[5]; t01.u[2] = D[6]; t01.u[3] = D[7];
        }
        {
            unsigned D[8];
#pragma unroll
            for (int dw = 0; dw < 8; ++dw) D[dw] = cvt_pk(p1[2 * dw], p1[2 * dw + 1]);
            pl32swap(D[0], D[2]); pl32swap(D[1], D[3]);
            pl32swap(D[4], D[6]); pl32swap(D[5], D[7]);
            t10.u[0] = D[0]; t10.u[1] = D[1]; t10.u[2] = D[2]; t10.u[3] = D[3];
            t11.u[0] = D[4]; t11.u[1] = D[5]; t11.u[2] = D[6]; t11.u[3] = D[7];
        }

        __syncthreads();                             // V tile staged & visible

        // ---- V frags from LDS + PV
        bf16x8 vf[8];
#pragma unroll
        for (int ht = 0; ht < 2; ++ht)
#pragma unroll
            for (int ksl = 0; ksl < 4; ++ksl)
                vf[ht * 4 + ksl] = *(const bf16x8*)(vbuf + (ht * 32 + l31) * 128
                                                    + ((ksl * 32 + hi * 16) ^ swz));
        oacc0 = __builtin_amdgcn_mfma_f32_32x32x16_bf16(vf[0], t00.v, oacc0, 0, 0, 0);
        oacc1 = __builtin_amdgcn_mfma_f32_32x32x16_bf16(vf[4], t00.v, oacc1, 0, 0, 0);
        oacc0 = __builtin_amdgcn_mfma_f32_32x32x16_bf16(vf[1], t01.v, oacc0, 0, 0, 0);
        oacc1 = __builtin_amdgcn_mfma_f32_32x32x16_bf16(vf[5], t01.v, oacc1, 0, 0, 0);
        oacc0 = __builtin_amdgcn_mfma_f32_32x32x16_bf16(vf[2], t10.v, oacc0, 0, 0, 0);
        oacc1 = __builtin_amdgcn_mfma_f32_32x32x16_bf16(vf[6], t10.v, oacc1, 0, 0, 0);
        oacc0 = __builtin_amdgcn_mfma_f32_32x32x16_bf16(vf[3], t11.v, oacc0, 0, 0, 0);
        oacc1 = __builtin_amdgcn_mfma_f32_32x32x16_bf16(vf[7], t11.v, oacc1, 0, 0, 0);

        __syncthreads();                             // reads drained before next overwrite
    }

    // ---- stage partials (aliases staging LDS): osm[4 sp][64 q][68], mlsm[4 sp][64 q][2]
    float* osm = (float*)smraw;
    float* mlsm = (float*)(smraw + 69632);
    {
        float* ow = osm + (size_t)(sp * 64 + qt * 32 + l31) * 68;
#pragma unroll
        for (int r = 0; r < 16; ++r) {
            int h = (r & 3) + 8 * (r >> 2) + 4 * hi;
            ow[h] = oacc0[r];
            ow[32 + h] = oacc1[r];
        }
        if (hi == 0) {
            mlsm[(sp * 64 + qt * 32 + l31) * 2] = m;
            mlsm[(sp * 64 + qt * 32 + l31) * 2 + 1] = l;
        }
    }
    __syncthreads();

    // ---- merge 4 sp-partials: thread = (q = t>>3, hb = (t&7)*8)
    {
        int tq = threadIdx.x >> 3, hb = (threadIdx.x & 7) * 8;
        float mw[4], lw[4];
#pragma unroll
        for (int w2 = 0; w2 < 4; ++w2) {
            mw[w2] = mlsm[(w2 * 64 + tq) * 2];
            lw[w2] = mlsm[(w2 * 64 + tq) * 2 + 1];
        }
        float M = fmaxf(fmaxf(mw[0], mw[1]), fmaxf(mw[2], mw[3]));
        f32x4 oa = (f32x4){0.f, 0.f, 0.f, 0.f}, ob = (f32x4){0.f, 0.f, 0.f, 0.f};
        float lsum = 0.f;
#pragma unroll
        for (int w2 = 0; w2 < 4; ++w2) {
            float a = exp2f(mw[w2] - M);
            lsum += a * lw[w2];
            const float* src = osm + (size_t)(w2 * 64 + tq) * 68 + hb;
            f32x4 x0 = *(const f32x4*)src;
            f32x4 x1 = *(const f32x4*)(src + 4);
#pragma unroll
            for (int j = 0; j < 4; ++j) { oa[j] += a * x0[j]; ob[j] += a * x1[j]; }
        }
        float inv = 1.f / lsum;
        f32x4 r0, r1;
#pragma unroll
        for (int j = 0; j < 4; ++j) { r0[j] = oa[j] * inv; r1[j] = ob[j] * inv; }
        float* op = out + (qrow0 + tq) * 64 + hb;
        *(f32x4*)op = r0;
        *(f32x4*)(op + 4) = r1;
    }
}

extern "C" void kernel_launch(void* const* d_in, const int* in_sizes, int n_in,
                              void* d_out, int out_size, void* d_ws, size_t ws_size,
                              hipStream_t stream) {
    const float* x  = (const float*)d_in[0];
    const float* Wq = (const float*)d_in[1];
    const float* bq = (const float*)d_in[2];
    const float* Wk = (const float*)d_in[3];
    const float* bk = (const float*)d_in[4];
    const float* Wv = (const float*)d_in[5];
    const float* bv = (const float*)d_in[6];

    short* ws = (short*)d_ws;
    short* Wt = ws;                       // 192*1024
    short* Qb = Wt + 192 * 1024;          // 16384*64
    short* Kb = Qb + 16384 * 64;
    short* Vt = Kb + 16384 * 64;          // [4][64][4096] transposed

    prep_w<<<48, 256, 0, stream>>>(Wq, Wk, Wv, Wt);
    proj_kernel<<<256, 512, 0, stream>>>(x, Wt, bq, bk, bv, Qb, Kb, Vt);
    attn_kernel<<<256, 512, 0, stream>>>(Qb, Kb, Vt, (float*)d_out);
}